// Round 6
// baseline (857.299 us; speedup 1.0000x reference)
//
#include <hip/hip_runtime.h>
#include <stdint.h>

// CrossAttention seq-len-1: softmax over singleton axis == 1, so attention
// reduces to   attn = x_other @ (out_w @ wv).T + (out_w @ bv + out_b).
// Merged-launch pipeline (A/B streams fused via blockIdx.z/y):
//   prep: transpose2, cast6, combine2, prepGEMM(z=2)
//   cast2 -> attnGEMM(z=2) -> LN0(y=2) -> FFN1(z=2) -> FFN2(z=2,bf16 out) -> LN2(y=2,f32 out)
// 10 launches total. All GEMMs bf16 MFMA 16x16x32, fp32 accumulate.
//
// GEMM: 256x128 block tile, 4 waves each 64x128.
//  - A-fragments: DIRECT global->register (each wave owns 64 distinct A-rows;
//    zero cross-wave reuse, so LDS staging of A was pure overhead). Ping-pong
//    reg sets (af0/af1), prefetched one K-step ahead -> L2 latency hides under
//    the previous step's MFMA cluster.
//  - B (shared by all 4 waves): triple-buffered LDS (3 x 8KB), depth-2 prefetch
//    via global_load_lds, counted s_waitcnt vmcnt(2) (never 0 mid-loop; the 2
//    newest B-stage loads stay in flight across the barrier; af loads are older
//    and therefore retired by the same counted wait).
//  - bf fragments loaded just-in-time inside the MFMA j-loop (reg budget <=256:
//    acc 128 + af 32 + bf ~8 + addr).
// s_setprio(1) around the MFMA cluster. XCD-aware bijective swizzle (T1):
// each XCD owns a contiguous y-chunk -> each A-panel fetched by ONE XCD's L2.

#define E 512
#define LNEPS 1e-5f

typedef unsigned short u16;
using u16x8   = __attribute__((ext_vector_type(8))) u16;
using shortx8 = __attribute__((ext_vector_type(8))) short;
using floatx4 = __attribute__((ext_vector_type(4))) float;

__device__ __forceinline__ float bf2f(u16 u) {
  uint32_t x = ((uint32_t)u) << 16;
  return __builtin_bit_cast(float, x);
}
__device__ __forceinline__ u16 f2bf(float f) {  // round-to-nearest-even
  uint32_t x = __builtin_bit_cast(uint32_t, f);
  x += 0x7fffu + ((x >> 16) & 1u);
  return (u16)(x >> 16);
}

__device__ __forceinline__ void gl_lds16(const u16* g, u16* l) {
  // async global->LDS, 16B per lane; LDS dest = wave-uniform base + lane*16
  __builtin_amdgcn_global_load_lds(
      (__attribute__((address_space(1))) uint32_t*)g,
      (__attribute__((address_space(3))) uint32_t*)l, 16, 0, 0);
}

// C[m,n] = sum_k A[m,k]*W[n,k] + bias[n]   (A: MxK bf16, W: NxK bf16 row-major)
// 256x128 block tile, BK=32, 4 waves each 64x128. bz selects stream.
template <bool RELU>
__global__ __launch_bounds__(256) void gemm_bt(const u16* __restrict__ A0,
                                               const u16* __restrict__ W0,
                                               const float* __restrict__ bias0,
                                               u16* __restrict__ C0,
                                               const u16* __restrict__ A1,
                                               const u16* __restrict__ W1,
                                               const float* __restrict__ bias1,
                                               u16* __restrict__ C1,
                                               int M, int N, int K, int ldc) {
  // ---- XCD-aware bijective swizzle (T1) ----
  const int gx = gridDim.x, gy = gridDim.y, gz = gridDim.z;
  const int T = gx * gy * gz;
  const int l = blockIdx.x + gx * (blockIdx.y + gy * blockIdx.z);
  int bx, by, bz;
  if ((T & 7) == 0) {
    const int g = (l & 7) * (T >> 3) + (l >> 3);  // XCD (l&7) owns contiguous g-chunk
    bx = g % gx;
    const int rest = g / gx;
    by = rest % gy;
    bz = rest / gy;
  } else {
    bx = blockIdx.x; by = blockIdx.y; bz = blockIdx.z;
  }

  // 3 B-buffers x (128 x 32 u16 = 8KB) = 24 KB total
  __shared__ u16 sbuf[3 * 4096];
  const u16* A = bz ? A1 : A0;
  const u16* W = bz ? W1 : W0;
  const float* bias = bz ? bias1 : bias0;
  u16* Cout = bz ? C1 : C0;

  const int tid  = threadIdx.x;
  const int wave = tid >> 6;
  const int lane = tid & 63;
  const int m0 = by * 256;   // M-tile
  const int n0 = bx * 128;   // N-tile
  const int wm = wave * 64;
  const int fm   = lane & 15;
  const int quad = lane >> 4;

  const floatx4 zero = {0.f, 0.f, 0.f, 0.f};
  floatx4 acc[4][8];
#pragma unroll
  for (int i = 0; i < 4; ++i)
#pragma unroll
    for (int j = 0; j < 8; ++j) acc[i][j] = zero;

  // A-fragment base: lane reads A[m0+wm+i*16+fm][kk + quad*8 .. +7]  (16B)
  const u16* Abase = A + (size_t)(m0 + wm + fm) * K + quad * 8;
  // B staging map (linear LDS, 16B/lane): each issue covers 16 rows x 32 cols.
  const int r4 = lane >> 2;          // 0..15
  const int c0 = (lane & 3) << 3;    // 0,8,16,24
  const u16* WpB = W + (size_t)(n0 + wave * 32 + r4) * K + c0;
  const size_t row16 = (size_t)16 * K;
  const int nt = K >> 5;             // BK=32 tiles (16 or 32 here; always even)

  shortx8 af0[4], af1[4];
  auto LOADA = [&](shortx8 (&dst)[4], int kko) {
#pragma unroll
    for (int i = 0; i < 4; ++i)
      dst[i] = *(const shortx8*)(Abase + (size_t)i * 16 * K + kko);
  };
  auto STAGEB = [&](const u16* wp, int b) {
    u16* base = sbuf + b * 4096 + wave * 1024;
    gl_lds16(wp, base);
    gl_lds16(wp + row16, base + 512);
  };
  auto COMPUTE = [&](int b, const shortx8 (&afc)[4]) {
    const u16* bB = sbuf + b * 4096;
    __builtin_amdgcn_s_setprio(1);
#pragma unroll
    for (int j = 0; j < 8; ++j) {
      const shortx8 bf = *(const shortx8*)(bB + (j * 16 + fm) * 32 + quad * 8);
#pragma unroll
      for (int i = 0; i < 4; ++i)
        acc[i][j] = __builtin_amdgcn_mfma_f32_16x16x32_bf16(afc[i], bf, acc[i][j], 0, 0, 0);
    }
    __builtin_amdgcn_s_setprio(0);
  };

  // prologue: af(0) + B(0)->buf0, B(1)->buf1  (order: af oldest, then B0, B1)
  LOADA(af0, 0);
  STAGEB(WpB, 0);
  STAGEB(WpB + 32, 1);
  const u16* Ws = WpB + 64;
  int sb = 2, cb = 0;
  int kk = 32;

  for (int t = 0; t < nt; t += 2) {
    // ---- even step t: consumes af0 + buf cb; B(t+2)'s 2 loads stay in flight
    asm volatile("s_waitcnt vmcnt(2)\n\ts_barrier" ::: "memory");
    LOADA(af1, kk);                 // af(t+1): t+1 <= nt-1 always
    kk += 32;
    if (t + 2 < nt) {
      STAGEB(Ws, sb);
      Ws += 32;
      sb = (sb == 2) ? 0 : sb + 1;
    }
    COMPUTE(cb, af0);
    cb = (cb == 2) ? 0 : cb + 1;
    // ---- odd step t+1: consumes af1 + buf cb
    if (t + 3 < nt)
      asm volatile("s_waitcnt vmcnt(2)\n\ts_barrier" ::: "memory");
    else
      asm volatile("s_waitcnt vmcnt(0)\n\ts_barrier" ::: "memory");
    if (t + 2 < nt) {
      LOADA(af0, kk);               // af(t+2)
      kk += 32;
    }
    if (t + 3 < nt) {
      STAGEB(Ws, sb);               // B(t+3)
      Ws += 32;
      sb = (sb == 2) ? 0 : sb + 1;
    }
    COMPUTE(cb, af1);
    cb = (cb == 2) ? 0 : cb + 1;
  }

  // epilogue: C/D layout col=lane&15, row=quad*4+reg  (m89/m91 verified)
#pragma unroll
  for (int j = 0; j < 8; ++j) {
    const int col = n0 + j * 16 + fm;
    const float bj = bias ? bias[col] : 0.f;
#pragma unroll
    for (int i = 0; i < 4; ++i) {
      const int rb = m0 + wm + i * 16 + quad * 4;
#pragma unroll
      for (int r = 0; r < 4; ++r) {
        float v = acc[i][j][r] + bj;
        if (RELU) v = fmaxf(v, 0.f);
        Cout[(size_t)(rb + r) * ldc + col] = f2bf(v);
      }
    }
  }
}

// MODE 0: out_bf16[row*E] = LN(resid_f32[row*E] + add_bf16[row*E])
// MODE 2: out_f32[row*ld] = LN(resid_bf16[row*E] + add_bf16[row*E])
// blockIdx.y selects stream. One wave per row of 512; lane handles 8 elems.
template <int MODE>
__global__ __launch_bounds__(256) void ln_add_kernel(
    const void* __restrict__ resid0, const void* __restrict__ resid1,
    const u16* __restrict__ add0, const u16* __restrict__ add1,
    const float* __restrict__ g0, const float* __restrict__ b0,
    const float* __restrict__ g1, const float* __restrict__ b1,
    void* __restrict__ out0, void* __restrict__ out1, int ld) {
  const int ss = blockIdx.y;
  const void* resid = ss ? resid1 : resid0;
  const u16* addv = ss ? add1 : add0;
  const float* g = ss ? g1 : g0;
  const float* b = ss ? b1 : b0;
  void* outp = ss ? out1 : out0;

  const int wave = threadIdx.x >> 6;
  const int lane = threadIdx.x & 63;
  const size_t row = (size_t)blockIdx.x * 4 + wave;
  const int col = lane * 8;
  float x[8];
  const u16x8 a = *(const u16x8*)(addv + row * E + col);
  if (MODE == 0) {
    const float* rp = (const float*)resid + row * E + col;
    const float4 r0 = *(const float4*)rp;
    const float4 r1 = *(const float4*)(rp + 4);
    x[0] = r0.x + bf2f(a[0]); x[1] = r0.y + bf2f(a[1]);
    x[2] = r0.z + bf2f(a[2]); x[3] = r0.w + bf2f(a[3]);
    x[4] = r1.x + bf2f(a[4]); x[5] = r1.y + bf2f(a[5]);
    x[6] = r1.z + bf2f(a[6]); x[7] = r1.w + bf2f(a[7]);
  } else {
    const u16x8 rr = *(const u16x8*)((const u16*)resid + row * E + col);
#pragma unroll
    for (int i = 0; i < 8; ++i) x[i] = bf2f(rr[i]) + bf2f(a[i]);
  }
  float s = 0.f, sq = 0.f;
#pragma unroll
  for (int i = 0; i < 8; ++i) {
    s += x[i];
    sq += x[i] * x[i];
  }
#pragma unroll
  for (int off = 32; off > 0; off >>= 1) {
    s += __shfl_xor(s, off);
    sq += __shfl_xor(sq, off);
  }
  const float mean = s * (1.f / E);
  const float var = sq * (1.f / E) - mean * mean;
  const float rs = rsqrtf(var + LNEPS);
  const float4 g0v = *(const float4*)(g + col);
  const float4 g1v = *(const float4*)(g + col + 4);
  const float4 b0v = *(const float4*)(b + col);
  const float4 b1v = *(const float4*)(b + col + 4);
  float y[8];
  y[0] = (x[0] - mean) * rs * g0v.x + b0v.x;
  y[1] = (x[1] - mean) * rs * g0v.y + b0v.y;
  y[2] = (x[2] - mean) * rs * g0v.z + b0v.z;
  y[3] = (x[3] - mean) * rs * g0v.w + b0v.w;
  y[4] = (x[4] - mean) * rs * g1v.x + b1v.x;
  y[5] = (x[5] - mean) * rs * g1v.y + b1v.y;
  y[6] = (x[6] - mean) * rs * g1v.z + b1v.z;
  y[7] = (x[7] - mean) * rs * g1v.w + b1v.w;
  if (MODE == 0) {
    u16x8 o;
#pragma unroll
    for (int i = 0; i < 8; ++i) o[i] = f2bf(y[i]);
    *(u16x8*)((u16*)outp + row * E + col) = o;
  } else {
    float* op = (float*)outp + row * ld + col;
    *(float4*)op = make_float4(y[0], y[1], y[2], y[3]);
    *(float4*)(op + 4) = make_float4(y[4], y[5], y[6], y[7]);
  }
}

// two input casts in one launch (blockIdx.y selects)
__global__ __launch_bounds__(256) void cast2_kernel(const float* __restrict__ in0,
                                                    const float* __restrict__ in1,
                                                    u16* __restrict__ o0,
                                                    u16* __restrict__ o1) {
  const float* in = blockIdx.y ? in1 : in0;
  u16* out = blockIdx.y ? o1 : o0;
  const size_t i = ((size_t)blockIdx.x * 256 + threadIdx.x) * 8;
  const float4 a = *(const float4*)(in + i);
  const float4 c = *(const float4*)(in + i + 4);
  u16x8 o;
  o[0] = f2bf(a.x); o[1] = f2bf(a.y); o[2] = f2bf(a.z); o[3] = f2bf(a.w);
  o[4] = f2bf(c.x); o[5] = f2bf(c.y); o[6] = f2bf(c.z); o[7] = f2bf(c.w);
  *(u16x8*)(out + i) = o;
}

// 6 weight casts in one launch: blocks [0,128) s0, [128,256) s1 (E*E each),
// [256,512) s2, [512,768) s3, [768,1024) s4, [1024,1280) s5 (2E*E each)
__global__ __launch_bounds__(256) void cast6_kernel(
    const float* __restrict__ s0, u16* __restrict__ d0,
    const float* __restrict__ s1, u16* __restrict__ d1,
    const float* __restrict__ s2, u16* __restrict__ d2,
    const float* __restrict__ s3, u16* __restrict__ d3,
    const float* __restrict__ s4, u16* __restrict__ d4,
    const float* __restrict__ s5, u16* __restrict__ d5) {
  int b = blockIdx.x;
  const float* in;
  u16* out;
  if (b < 256) {
    in = (b < 128) ? s0 : s1;
    out = (b < 128) ? d0 : d1;
    b &= 127;
  } else {
    const int t = (b - 256) >> 8;  // 0..3
    in = (t == 0) ? s2 : (t == 1) ? s3 : (t == 2) ? s4 : s5;
    out = (t == 0) ? d2 : (t == 1) ? d3 : (t == 2) ? d4 : d5;
    b = (b - 256) & 255;
  }
  const size_t i = ((size_t)b * 256 + threadIdx.x) * 8;
  const float4 a = *(const float4*)(in + i);
  const float4 c = *(const float4*)(in + i + 4);
  u16x8 o;
  o[0] = f2bf(a.x); o[1] = f2bf(a.y); o[2] = f2bf(a.z); o[3] = f2bf(a.w);
  o[4] = f2bf(c.x); o[5] = f2bf(c.y); o[6] = f2bf(c.z); o[7] = f2bf(c.w);
  *(u16x8*)(out + i) = o;
}

// out[k][j] = bf16(in[j][k]) for ExE; blockIdx.z selects stream
__global__ __launch_bounds__(256) void transpose_cast2_kernel(const float* __restrict__ in0,
                                                              u16* __restrict__ out0,
                                                              const float* __restrict__ in1,
                                                              u16* __restrict__ out1) {
  __shared__ float t[32][33];
  const float* in = blockIdx.z ? in1 : in0;
  u16* out = blockIdx.z ? out1 : out0;
  const int bx = blockIdx.x * 32;
  const int by = blockIdx.y * 32;
  const int x = threadIdx.x & 31;
  const int y0 = threadIdx.x >> 5;
#pragma unroll
  for (int y = y0; y < 32; y += 8) t[y][x] = in[(size_t)(by + y) * E + bx + x];
  __syncthreads();
#pragma unroll
  for (int y = y0; y < 32; y += 8) out[(size_t)(bx + y) * E + by + x] = f2bf(t[x][y]);
}

// bc[n] = dot(outw[n,:], bv) + outb[n]; n in [0,1024): n<512 stream A else B
__global__ __launch_bounds__(256) void combine_bias2_kernel(
    const float* __restrict__ outw1, const float* __restrict__ bv1,
    const float* __restrict__ outb1, float* __restrict__ bc1,
    const float* __restrict__ outw2, const float* __restrict__ bv2,
    const float* __restrict__ outb2, float* __restrict__ bc2) {
  int n = blockIdx.x * 256 + threadIdx.x;
  const float* outw = (n < E) ? outw1 : outw2;
  const float* bv = (n < E) ? bv1 : bv2;
  const float* outb = (n < E) ? outb1 : outb2;
  float* bc = (n < E) ? bc1 : bc2;
  n &= (E - 1);
  const float* wr = outw + (size_t)n * E;
  float s = 0.f;
  for (int j = 0; j < E; j += 4) {
    const float4 w4 = *(const float4*)(wr + j);
    const float4 v4 = *(const float4*)(bv + j);
    s += w4.x * v4.x + w4.y * v4.y + w4.z * v4.z + w4.w * v4.w;
  }
  bc[n] = s + outb[n];
}

extern "C" void kernel_launch(void* const* d_in, const int* in_sizes, int n_in,
                              void* d_out, int out_size, void* d_ws, size_t ws_size,
                              hipStream_t stream) {
  const float* dna      = (const float*)d_in[0];
  const float* mol      = (const float*)d_in[1];
  const float* a1_in_w  = (const float*)d_in[2];
  const float* a1_in_b  = (const float*)d_in[3];
  const float* a1_out_w = (const float*)d_in[4];
  const float* a1_out_b = (const float*)d_in[5];
  const float* a2_in_w  = (const float*)d_in[6];
  const float* a2_in_b  = (const float*)d_in[7];
  const float* a2_out_w = (const float*)d_in[8];
  const float* a2_out_b = (const float*)d_in[9];
  const float* ln1_g = (const float*)d_in[10];
  const float* ln1_b = (const float*)d_in[11];
  const float* ln2_g = (const float*)d_in[12];
  const float* ln2_b = (const float*)d_in[13];
  const float* ln3_g = (const float*)d_in[14];
  const float* ln3_b = (const float*)d_in[15];
  const float* ln4_g = (const float*)d_in[16];
  const float* ln4_b = (const float*)d_in[17];
  const float* f1_w1 = (const float*)d_in[18];
  const float* f1_b1 = (const float*)d_in[19];
  const float* f1_w2 = (const float*)d_in[20];
  const float* f1_b2 = (const float*)d_in[21];
  const float* f2_w1 = (const float*)d_in[22];
  const float* f2_b1 = (const float*)d_in[23];
  const float* f2_w2 = (const float*)d_in[24];
  const float* f2_b2 = (const float*)d_in[25];

  const int M = in_sizes[0] / E;  // 32768

  char* ws = (char*)d_ws;
  auto bump = [&](size_t sz) {
    char* p = ws;
    ws += (sz + 255) & ~(size_t)255;
    return p;
  };
  u16* wvT1   = (u16*)bump((size_t)E * E * 2);
  u16* wvT2   = (u16*)bump((size_t)E * E * 2);
  u16* outw1b = (u16*)bump((size_t)E * E * 2);
  u16* outw2b = (u16*)bump((size_t)E * E * 2);
  u16* Wc1    = (u16*)bump((size_t)E * E * 2);
  u16* Wc2    = (u16*)bump((size_t)E * E * 2);
  u16* fw11   = (u16*)bump((size_t)2 * E * E * 2);
  u16* fw12   = (u16*)bump((size_t)2 * E * E * 2);
  u16* fw21   = (u16*)bump((size_t)2 * E * E * 2);
  u16* fw22   = (u16*)bump((size_t)2 * E * E * 2);
  float* bc1  = (float*)bump(E * 4);
  float* bc2  = (float*)bump(E * 4);
  u16* X1  = (u16*)bump((size_t)M * E * 2);      // dna_bf, later y1
  u16* X2  = (u16*)bump((size_t)M * E * 2);      // mol_bf, later y2
  u16* Hb0 = (u16*)bump((size_t)M * 2 * E * 2);  // stream A FFN hidden
  u16* Hb1 = (u16*)bump((size_t)M * 2 * E * 2);  // stream B FFN hidden
  u16* Hc0 = (u16*)bump((size_t)M * E * 2);      // stream A attn out, later FFN2 out
  u16* Hc1 = (u16*)bump((size_t)M * E * 2);      // stream B attn out, later FFN2 out
  float* out_f = (float*)d_out;  // M x 2E, left=dna stream, right=mol stream

  // ---- weight prep (4 launches) ----
  transpose_cast2_kernel<<<dim3(16, 16, 2), 256, 0, stream>>>(
      a1_in_w + 2 * E * E, wvT1, a2_in_w + 2 * E * E, wvT2);
  cast6_kernel<<<1280, 256, 0, stream>>>(a1_out_w, outw1b, a2_out_w, outw2b,
                                         f1_w1, fw11, f1_w2, fw12, f2_w1, fw21, f2_w2, fw22);
  combine_bias2_kernel<<<4, 256, 0, stream>>>(a1_out_w, a1_in_b + 2 * E, a1_out_b, bc1,
                                              a2_out_w, a2_in_b + 2 * E, a2_out_b, bc2);
  // Wc[n,k] = sum_j out_w[n,j] * wv[j,k]  via gemm_bt(out_w, wv^T)  (M=N=K=512)
  gemm_bt<false><<<dim3(4, 2, 2), 256, 0, stream>>>(
      outw1b, wvT1, nullptr, Wc1, outw2b, wvT2, nullptr, Wc2, E, E, E, E);

  // ---- activations (6 launches) ----
  cast2_kernel<<<dim3((unsigned)((size_t)M * E / 2048), 2), 256, 0, stream>>>(dna, mol, X1, X2);
  // attn (softmax==1 -> pure projection with combined weights); A-stream uses X2!
  gemm_bt<false><<<dim3(4, M / 256, 2), 256, 0, stream>>>(
      X2, Wc1, bc1, Hc0, X1, Wc2, bc2, Hc1, M, E, E, E);
  // y = LN(x + attn)  (overwrites the now-dead bf16 input casts)
  ln_add_kernel<0><<<dim3(M / 4, 2), 256, 0, stream>>>(
      dna, mol, Hc0, Hc1, ln1_g, ln1_b, ln2_g, ln2_b, X1, X2, E);
  // FFN hidden (relu)
  gemm_bt<true><<<dim3(8, M / 256, 2), 256, 0, stream>>>(
      X1, fw11, f1_b1, Hb0, X2, fw21, f2_b1, Hb1, M, 2 * E, E, 2 * E);
  // FFN out (bf16, overwrites dead attn buffers)
  gemm_bt<false><<<dim3(4, M / 256, 2), 256, 0, stream>>>(
      Hb0, fw12, f1_b2, Hc0, Hb1, fw22, f2_b2, Hc1, M, E, 2 * E, E);
  // final LN -> f32 d_out halves
  ln_add_kernel<2><<<dim3(M / 4, 2), 256, 0, stream>>>(
      X1, X2, Hc0, Hc1, ln3_g, ln3_b, ln4_g, ln4_b, out_f, out_f + E, 2 * E);
}

// Round 7
// 665.475 us; speedup vs baseline: 1.2883x; 1.2883x over previous
//
#include <hip/hip_runtime.h>
#include <stdint.h>

// CrossAttention seq-len-1: softmax over singleton axis == 1, so attention
// reduces to   attn = x_other @ (out_w @ wv).T + (out_w @ bv + out_b).
// Merged-launch pipeline (A/B streams fused via blockIdx.z/y):
//   prep: transpose2, cast6, combine2, prepGEMM(z=2)
//   cast2 -> attnGEMM(z=2) -> LN0(y=2, bf16 in-place) -> FFN1(z=2) ->
//   FFN2(z=2, bf16 out) -> LN2(y=2, f32 out)
// 10 launches total. All GEMMs bf16 MFMA 16x16x32, fp32 accumulate.
//
// GEMM: 256x128 block tile, 4 waves each 64x128 (acc[4][8] = 128 AGPR).
// REGISTER BUDGET IS THE BINDING CONSTRAINT: 124 VGPR + 128 AGPR = 252 <= 256
// keeps 2 waves/SIMD. (Round-6 lesson: A-in-reg ping-pong added +32 VGPR ->
// 284 > 256 -> 1 wave/SIMD -> 2x regression. Do not add live state.)
//  - A+B staged via global_load_lds into triple-buffered LDS (3 x 24KB),
//    depth-2 prefetch, counted s_waitcnt vmcnt(6) (never 0 mid-loop) + raw
//    s_barrier fused in one asm block.
//  - K is a TEMPLATE param: NT=K/32 constexpr + #pragma unroll 3 folds the
//    3-buffer rotation (t%3) to compile-time constants -> LDS addrs become
//    immediates, staging offsets fold into the 13-bit offset field, induction
//    vars DCE. Targets round-5's 25% VALUBusy (addr math on the critical path).
// s_setprio(1) around the MFMA cluster. XCD-aware bijective swizzle (T1):
// each XCD owns a contiguous y-chunk -> each A-panel fetched by ONE XCD's L2
// (proven round 5: FETCH 265 -> 48 MB).

#define E 512
#define LNEPS 1e-5f

typedef unsigned short u16;
using u16x8   = __attribute__((ext_vector_type(8))) u16;
using shortx8 = __attribute__((ext_vector_type(8))) short;
using floatx4 = __attribute__((ext_vector_type(4))) float;

__device__ __forceinline__ float bf2f(u16 u) {
  uint32_t x = ((uint32_t)u) << 16;
  return __builtin_bit_cast(float, x);
}
__device__ __forceinline__ u16 f2bf(float f) {  // round-to-nearest-even
  uint32_t x = __builtin_bit_cast(uint32_t, f);
  x += 0x7fffu + ((x >> 16) & 1u);
  return (u16)(x >> 16);
}

__device__ __forceinline__ void gl_lds16(const u16* g, u16* l) {
  // async global->LDS, 16B per lane; LDS dest = wave-uniform base + lane*16
  __builtin_amdgcn_global_load_lds(
      (__attribute__((address_space(1))) uint32_t*)g,
      (__attribute__((address_space(3))) uint32_t*)l, 16, 0, 0);
}

// C[m,n] = sum_k A[m,k]*W[n,k] + bias[n]   (A: MxK bf16, W: NxK bf16 row-major)
// 256x128 block tile, BK=32, 4 waves each 64x128. bz selects stream.
template <bool RELU, int K>
__global__ __launch_bounds__(256) void gemm_bt(const u16* __restrict__ A0,
                                               const u16* __restrict__ W0,
                                               const float* __restrict__ bias0,
                                               u16* __restrict__ C0,
                                               const u16* __restrict__ A1,
                                               const u16* __restrict__ W1,
                                               const float* __restrict__ bias1,
                                               u16* __restrict__ C1,
                                               int ldc) {
  // ---- XCD-aware bijective swizzle (T1) ----
  const int gx = gridDim.x, gy = gridDim.y, gz = gridDim.z;
  const int T = gx * gy * gz;
  const int l = blockIdx.x + gx * (blockIdx.y + gy * blockIdx.z);
  int bx, by, bz;
  if ((T & 7) == 0) {
    const int g = (l & 7) * (T >> 3) + (l >> 3);  // XCD (l&7) owns contiguous g-chunk
    bx = g % gx;
    const int rest = g / gx;
    by = rest % gy;
    bz = rest / gy;
  } else {
    bx = blockIdx.x; by = blockIdx.y; bz = blockIdx.z;
  }

  // 3 buffers x (A 256x32 = 16KB + B 128x32 = 8KB) = 72 KB
  __shared__ u16 sbuf[3 * 12288];
  const u16* A = bz ? A1 : A0;
  const u16* W = bz ? W1 : W0;
  const float* bias = bz ? bias1 : bias0;
  u16* Cout = bz ? C1 : C0;

  const int tid  = threadIdx.x;
  const int wave = tid >> 6;
  const int lane = tid & 63;
  const int m0 = by * 256;   // M-tile
  const int n0 = bx * 128;   // N-tile
  const int wm = wave * 64;
  const int fm   = lane & 15;
  const int quad = lane >> 4;

  const floatx4 zero = {0.f, 0.f, 0.f, 0.f};
  floatx4 acc[4][8];
#pragma unroll
  for (int i = 0; i < 4; ++i)
#pragma unroll
    for (int j = 0; j < 8; ++j) acc[i][j] = zero;

  // staging map (linear LDS, 16B/lane): each issue covers 16 rows x 32 cols.
  const int r4 = lane >> 2;          // 0..15
  const int c0 = (lane & 3) << 3;    // 0,8,16,24
  const u16* ApA = A + (size_t)(m0 + wave * 64 + r4) * K + c0;
  const u16* WpB = W + (size_t)(n0 + wave * 32 + r4) * K + c0;
  constexpr size_t row16 = (size_t)16 * K;
  constexpr int NT = K >> 5;         // BK=32 tiles (16 or 32; >= 3)

  auto STAGE = [&](int t, int b) {   // stage K-tile t into buffer b
    u16* base = sbuf + b * 12288;
    const u16* ap = ApA + t * 32;
    const u16* wp = WpB + t * 32;
#pragma unroll
    for (int q = 0; q < 4; ++q)
      gl_lds16(ap + (size_t)q * row16, base + (wave * 4 + q) * 512);
#pragma unroll
    for (int q = 0; q < 2; ++q)
      gl_lds16(wp + (size_t)q * row16, base + 8192 + (wave * 2 + q) * 512);
  };
  auto COMPUTE = [&](int b) {
    const u16* bA = sbuf + b * 12288;
    const u16* bB = bA + 8192;
    shortx8 af[4], bf[8];
#pragma unroll
    for (int i = 0; i < 4; ++i)
      af[i] = *(const shortx8*)(bA + (wm + i * 16 + fm) * 32 + quad * 8);
#pragma unroll
    for (int j = 0; j < 8; ++j)
      bf[j] = *(const shortx8*)(bB + (j * 16 + fm) * 32 + quad * 8);
    __builtin_amdgcn_s_setprio(1);
#pragma unroll
    for (int j = 0; j < 8; ++j)
#pragma unroll
      for (int i = 0; i < 4; ++i)
        acc[i][j] = __builtin_amdgcn_mfma_f32_16x16x32_bf16(af[i], bf[j], acc[i][j], 0, 0, 0);
    __builtin_amdgcn_s_setprio(0);
  };

  // prologue: tiles 0,1 -> buffers 0,1 (12 loads in flight)
  STAGE(0, 0);
  STAGE(1, 1);

  // main loop: unroll-3 folds t%3/(t+2)%3 to constants (NT constexpr).
#pragma unroll 3
  for (int t = 0; t < NT - 1; ++t) {
    // retire tile t's 6 loads (leave tile t+1's 6 in flight), then sync.
    asm volatile("s_waitcnt vmcnt(6)\n\ts_barrier" ::: "memory");
    if (t < NT - 2) STAGE(t + 2, (t + 2) % 3);
    COMPUTE(t % 3);
  }
  asm volatile("s_waitcnt vmcnt(0)\n\ts_barrier" ::: "memory");
  COMPUTE((NT - 1) % 3);

  // epilogue: C/D layout col=lane&15, row=quad*4+reg  (m89/m91 verified)
#pragma unroll
  for (int j = 0; j < 8; ++j) {
    const int col = n0 + j * 16 + fm;
    const float bj = bias ? bias[col] : 0.f;
#pragma unroll
    for (int i = 0; i < 4; ++i) {
      const int rb = m0 + wm + i * 16 + quad * 4;
#pragma unroll
      for (int r = 0; r < 4; ++r) {
        float v = acc[i][j][r] + bj;
        if (RELU) v = fmaxf(v, 0.f);
        Cout[(size_t)(rb + r) * ldc + col] = f2bf(v);
      }
    }
  }
}

// out = LN(resid_bf16 + add_bf16):  OUTF32=0 -> bf16 out (stride E, in-place on
// resid ok); OUTF32=1 -> f32 out (stride ld). blockIdx.y selects stream.
// One wave per row of 512; lane handles 8 consecutive elements.
template <int OUTF32>
__global__ __launch_bounds__(256) void ln_add_kernel(
    const u16* __restrict__ resid0, const u16* __restrict__ resid1,
    const u16* __restrict__ add0, const u16* __restrict__ add1,
    const float* __restrict__ g0, const float* __restrict__ b0,
    const float* __restrict__ g1, const float* __restrict__ b1,
    void* __restrict__ out0, void* __restrict__ out1, int ld) {
  const int ss = blockIdx.y;
  const u16* resid = ss ? resid1 : resid0;
  const u16* addv = ss ? add1 : add0;
  const float* g = ss ? g1 : g0;
  const float* b = ss ? b1 : b0;
  void* outp = ss ? out1 : out0;

  const int wave = threadIdx.x >> 6;
  const int lane = threadIdx.x & 63;
  const size_t row = (size_t)blockIdx.x * 4 + wave;
  const int col = lane * 8;
  float x[8];
  const u16x8 a = *(const u16x8*)(addv + row * E + col);
  const u16x8 rr = *(const u16x8*)(resid + row * E + col);
#pragma unroll
  for (int i = 0; i < 8; ++i) x[i] = bf2f(rr[i]) + bf2f(a[i]);
  float s = 0.f, sq = 0.f;
#pragma unroll
  for (int i = 0; i < 8; ++i) {
    s += x[i];
    sq += x[i] * x[i];
  }
#pragma unroll
  for (int off = 32; off > 0; off >>= 1) {
    s += __shfl_xor(s, off);
    sq += __shfl_xor(sq, off);
  }
  const float mean = s * (1.f / E);
  const float var = sq * (1.f / E) - mean * mean;
  const float rs = rsqrtf(var + LNEPS);
  const float4 g0v = *(const float4*)(g + col);
  const float4 g1v = *(const float4*)(g + col + 4);
  const float4 b0v = *(const float4*)(b + col);
  const float4 b1v = *(const float4*)(b + col + 4);
  float y[8];
  y[0] = (x[0] - mean) * rs * g0v.x + b0v.x;
  y[1] = (x[1] - mean) * rs * g0v.y + b0v.y;
  y[2] = (x[2] - mean) * rs * g0v.z + b0v.z;
  y[3] = (x[3] - mean) * rs * g0v.w + b0v.w;
  y[4] = (x[4] - mean) * rs * g1v.x + b1v.x;
  y[5] = (x[5] - mean) * rs * g1v.y + b1v.y;
  y[6] = (x[6] - mean) * rs * g1v.z + b1v.z;
  y[7] = (x[7] - mean) * rs * g1v.w + b1v.w;
  if (OUTF32 == 0) {
    u16x8 o;
#pragma unroll
    for (int i = 0; i < 8; ++i) o[i] = f2bf(y[i]);
    *(u16x8*)((u16*)outp + row * E + col) = o;
  } else {
    float* op = (float*)outp + row * ld + col;
    *(float4*)op = make_float4(y[0], y[1], y[2], y[3]);
    *(float4*)(op + 4) = make_float4(y[4], y[5], y[6], y[7]);
  }
}

// two input casts in one launch (blockIdx.y selects)
__global__ __launch_bounds__(256) void cast2_kernel(const float* __restrict__ in0,
                                                    const float* __restrict__ in1,
                                                    u16* __restrict__ o0,
                                                    u16* __restrict__ o1) {
  const float* in = blockIdx.y ? in1 : in0;
  u16* out = blockIdx.y ? o1 : o0;
  const size_t i = ((size_t)blockIdx.x * 256 + threadIdx.x) * 8;
  const float4 a = *(const float4*)(in + i);
  const float4 c = *(const float4*)(in + i + 4);
  u16x8 o;
  o[0] = f2bf(a.x); o[1] = f2bf(a.y); o[2] = f2bf(a.z); o[3] = f2bf(a.w);
  o[4] = f2bf(c.x); o[5] = f2bf(c.y); o[6] = f2bf(c.z); o[7] = f2bf(c.w);
  *(u16x8*)(out + i) = o;
}

// 6 weight casts in one launch: blocks [0,128) s0, [128,256) s1 (E*E each),
// [256,512) s2, [512,768) s3, [768,1024) s4, [1024,1280) s5 (2E*E each)
__global__ __launch_bounds__(256) void cast6_kernel(
    const float* __restrict__ s0, u16* __restrict__ d0,
    const float* __restrict__ s1, u16* __restrict__ d1,
    const float* __restrict__ s2, u16* __restrict__ d2,
    const float* __restrict__ s3, u16* __restrict__ d3,
    const float* __restrict__ s4, u16* __restrict__ d4,
    const float* __restrict__ s5, u16* __restrict__ d5) {
  int b = blockIdx.x;
  const float* in;
  u16* out;
  if (b < 256) {
    in = (b < 128) ? s0 : s1;
    out = (b < 128) ? d0 : d1;
    b &= 127;
  } else {
    const int t = (b - 256) >> 8;  // 0..3
    in = (t == 0) ? s2 : (t == 1) ? s3 : (t == 2) ? s4 : s5;
    out = (t == 0) ? d2 : (t == 1) ? d3 : (t == 2) ? d4 : d5;
    b = (b - 256) & 255;
  }
  const size_t i = ((size_t)b * 256 + threadIdx.x) * 8;
  const float4 a = *(const float4*)(in + i);
  const float4 c = *(const float4*)(in + i + 4);
  u16x8 o;
  o[0] = f2bf(a.x); o[1] = f2bf(a.y); o[2] = f2bf(a.z); o[3] = f2bf(a.w);
  o[4] = f2bf(c.x); o[5] = f2bf(c.y); o[6] = f2bf(c.z); o[7] = f2bf(c.w);
  *(u16x8*)(out + i) = o;
}

// out[k][j] = bf16(in[j][k]) for ExE; blockIdx.z selects stream
__global__ __launch_bounds__(256) void transpose_cast2_kernel(const float* __restrict__ in0,
                                                              u16* __restrict__ out0,
                                                              const float* __restrict__ in1,
                                                              u16* __restrict__ out1) {
  __shared__ float t[32][33];
  const float* in = blockIdx.z ? in1 : in0;
  u16* out = blockIdx.z ? out1 : out0;
  const int bx = blockIdx.x * 32;
  const int by = blockIdx.y * 32;
  const int x = threadIdx.x & 31;
  const int y0 = threadIdx.x >> 5;
#pragma unroll
  for (int y = y0; y < 32; y += 8) t[y][x] = in[(size_t)(by + y) * E + bx + x];
  __syncthreads();
#pragma unroll
  for (int y = y0; y < 32; y += 8) out[(size_t)(bx + y) * E + by + x] = f2bf(t[x][y]);
}

// bc[n] = dot(outw[n,:], bv) + outb[n]; n in [0,1024): n<512 stream A else B
__global__ __launch_bounds__(256) void combine_bias2_kernel(
    const float* __restrict__ outw1, const float* __restrict__ bv1,
    const float* __restrict__ outb1, float* __restrict__ bc1,
    const float* __restrict__ outw2, const float* __restrict__ bv2,
    const float* __restrict__ outb2, float* __restrict__ bc2) {
  int n = blockIdx.x * 256 + threadIdx.x;
  const float* outw = (n < E) ? outw1 : outw2;
  const float* bv = (n < E) ? bv1 : bv2;
  const float* outb = (n < E) ? outb1 : outb2;
  float* bc = (n < E) ? bc1 : bc2;
  n &= (E - 1);
  const float* wr = outw + (size_t)n * E;
  float s = 0.f;
  for (int j = 0; j < E; j += 4) {
    const float4 w4 = *(const float4*)(wr + j);
    const float4 v4 = *(const float4*)(bv + j);
    s += w4.x * v4.x + w4.y * v4.y + w4.z * v4.z + w4.w * v4.w;
  }
  bc[n] = s + outb[n];
}

extern "C" void kernel_launch(void* const* d_in, const int* in_sizes, int n_in,
                              void* d_out, int out_size, void* d_ws, size_t ws_size,
                              hipStream_t stream) {
  const float* dna      = (const float*)d_in[0];
  const float* mol      = (const float*)d_in[1];
  const float* a1_in_w  = (const float*)d_in[2];
  const float* a1_in_b  = (const float*)d_in[3];
  const float* a1_out_w = (const float*)d_in[4];
  const float* a1_out_b = (const float*)d_in[5];
  const float* a2_in_w  = (const float*)d_in[6];
  const float* a2_in_b  = (const float*)d_in[7];
  const float* a2_out_w = (const float*)d_in[8];
  const float* a2_out_b = (const float*)d_in[9];
  const float* ln1_g = (const float*)d_in[10];
  const float* ln1_b = (const float*)d_in[11];
  const float* ln2_g = (const float*)d_in[12];
  const float* ln2_b = (const float*)d_in[13];
  const float* ln3_g = (const float*)d_in[14];
  const float* ln3_b = (const float*)d_in[15];
  const float* ln4_g = (const float*)d_in[16];
  const float* ln4_b = (const float*)d_in[17];
  const float* f1_w1 = (const float*)d_in[18];
  const float* f1_b1 = (const float*)d_in[19];
  const float* f1_w2 = (const float*)d_in[20];
  const float* f1_b2 = (const float*)d_in[21];
  const float* f2_w1 = (const float*)d_in[22];
  const float* f2_b1 = (const float*)d_in[23];
  const float* f2_w2 = (const float*)d_in[24];
  const float* f2_b2 = (const float*)d_in[25];

  const int M = in_sizes[0] / E;  // 32768

  char* ws = (char*)d_ws;
  auto bump = [&](size_t sz) {
    char* p = ws;
    ws += (sz + 255) & ~(size_t)255;
    return p;
  };
  u16* wvT1   = (u16*)bump((size_t)E * E * 2);
  u16* wvT2   = (u16*)bump((size_t)E * E * 2);
  u16* outw1b = (u16*)bump((size_t)E * E * 2);
  u16* outw2b = (u16*)bump((size_t)E * E * 2);
  u16* Wc1    = (u16*)bump((size_t)E * E * 2);
  u16* Wc2    = (u16*)bump((size_t)E * E * 2);
  u16* fw11   = (u16*)bump((size_t)2 * E * E * 2);
  u16* fw12   = (u16*)bump((size_t)2 * E * E * 2);
  u16* fw21   = (u16*)bump((size_t)2 * E * E * 2);
  u16* fw22   = (u16*)bump((size_t)2 * E * E * 2);
  float* bc1  = (float*)bump(E * 4);
  float* bc2  = (float*)bump(E * 4);
  u16* X1  = (u16*)bump((size_t)M * E * 2);      // dna_bf, later y1
  u16* X2  = (u16*)bump((size_t)M * E * 2);      // mol_bf, later y2
  u16* Hb0 = (u16*)bump((size_t)M * 2 * E * 2);  // stream A FFN hidden
  u16* Hb1 = (u16*)bump((size_t)M * 2 * E * 2);  // stream B FFN hidden
  u16* Hc0 = (u16*)bump((size_t)M * E * 2);      // stream A attn out, later FFN2 out
  u16* Hc1 = (u16*)bump((size_t)M * E * 2);      // stream B attn out, later FFN2 out
  float* out_f = (float*)d_out;  // M x 2E, left=dna stream, right=mol stream

  // ---- weight prep (4 launches) ----
  transpose_cast2_kernel<<<dim3(16, 16, 2), 256, 0, stream>>>(
      a1_in_w + 2 * E * E, wvT1, a2_in_w + 2 * E * E, wvT2);
  cast6_kernel<<<1280, 256, 0, stream>>>(a1_out_w, outw1b, a2_out_w, outw2b,
                                         f1_w1, fw11, f1_w2, fw12, f2_w1, fw21, f2_w2, fw22);
  combine_bias2_kernel<<<4, 256, 0, stream>>>(a1_out_w, a1_in_b + 2 * E, a1_out_b, bc1,
                                              a2_out_w, a2_in_b + 2 * E, a2_out_b, bc2);
  // Wc[n,k] = sum_j out_w[n,j] * wv[j,k]  via gemm_bt(out_w, wv^T)  (M=N=K=512)
  gemm_bt<false, 512><<<dim3(4, 2, 2), 256, 0, stream>>>(
      outw1b, wvT1, nullptr, Wc1, outw2b, wvT2, nullptr, Wc2, E);

  // ---- activations (6 launches) ----
  cast2_kernel<<<dim3((unsigned)((size_t)M * E / 2048), 2), 256, 0, stream>>>(dna, mol, X1, X2);
  // attn (softmax==1 -> pure projection with combined weights); A-stream uses X2!
  gemm_bt<false, 512><<<dim3(4, M / 256, 2), 256, 0, stream>>>(
      X2, Wc1, bc1, Hc0, X1, Wc2, bc2, Hc1, E);
  // y = LN(x + attn), bf16 residual (X), in-place on X
  ln_add_kernel<0><<<dim3(M / 4, 2), 256, 0, stream>>>(
      X1, X2, Hc0, Hc1, ln1_g, ln1_b, ln2_g, ln2_b, X1, X2, E);
  // FFN hidden (relu)
  gemm_bt<true, 512><<<dim3(8, M / 256, 2), 256, 0, stream>>>(
      X1, fw11, f1_b1, Hb0, X2, fw21, f2_b1, Hb1, 2 * E);
  // FFN out (bf16, overwrites dead attn buffers)
  gemm_bt<false, 1024><<<dim3(4, M / 256, 2), 256, 0, stream>>>(
      Hb0, fw12, f1_b2, Hc0, Hb1, fw22, f2_b2, Hc1, E);
  // final LN -> f32 d_out halves
  ln_add_kernel<1><<<dim3(M / 4, 2), 256, 0, stream>>>(
      X1, X2, Hc0, Hc1, ln3_g, ln3_b, ln4_g, ln4_b, out_f, out_f + E, 2 * E);
}

// Round 8
// 605.613 us; speedup vs baseline: 1.4156x; 1.0988x over previous
//
#include <hip/hip_runtime.h>
#include <stdint.h>

// CrossAttention seq-len-1: softmax over singleton axis == 1, so attention
// reduces to   attn = x_other @ (out_w @ wv).T + (out_w @ bv + out_b).
// Merged-launch pipeline (A/B streams fused via blockIdx.z/y):
//   prep: transpose2, cast6, combine2, prepGEMM(z=2)
//   cast2 -> attnGEMM(z=2) -> LN0(y=2, bf16 in-place) -> FFN1(z=2) ->
//   FFN2(z=2, bf16 out) -> LN2(y=2, f32 out)
// 10 launches total. All GEMMs bf16 MFMA 16x16x32, fp32 accumulate.
//
// GEMM: 256x128 block tile, 4 waves each 64x128 (acc[4][8] = 128 AGPR).
// REGISTER BUDGET IS THE BINDING CONSTRAINT: 124 VGPR + 128 AGPR = 252 <= 256
// keeps 2 waves/SIMD. Rounds 6 (A-in-reg, +32 VGPR) and 7 (unroll-3, +32 VGPR)
// both crossed 256 -> 1 wave/SIMD -> 20-90% GEMM regression. This is the exact
// round-5 loop (runtime rotation, 124 VGPR, 105.6us FFN1) + __launch_bounds__
// (256,2) to pin the <=256-reg tier at compile time.
//  - A+B staged via global_load_lds into triple-buffered LDS (3 x 24KB),
//    depth-2 prefetch, counted s_waitcnt vmcnt(6) (never 0 mid-loop) + raw
//    s_barrier fused in one asm block.
// s_setprio(1) around the MFMA cluster. XCD-aware bijective swizzle (T1):
// each XCD owns a contiguous y-chunk -> each A-panel fetched by ONE XCD's L2
// (proven round 5: FETCH 265 -> 48 MB).

#define E 512
#define LNEPS 1e-5f

typedef unsigned short u16;
using u16x8   = __attribute__((ext_vector_type(8))) u16;
using shortx8 = __attribute__((ext_vector_type(8))) short;
using floatx4 = __attribute__((ext_vector_type(4))) float;

__device__ __forceinline__ float bf2f(u16 u) {
  uint32_t x = ((uint32_t)u) << 16;
  return __builtin_bit_cast(float, x);
}
__device__ __forceinline__ u16 f2bf(float f) {  // round-to-nearest-even
  uint32_t x = __builtin_bit_cast(uint32_t, f);
  x += 0x7fffu + ((x >> 16) & 1u);
  return (u16)(x >> 16);
}

__device__ __forceinline__ void gl_lds16(const u16* g, u16* l) {
  // async global->LDS, 16B per lane; LDS dest = wave-uniform base + lane*16
  __builtin_amdgcn_global_load_lds(
      (__attribute__((address_space(1))) uint32_t*)g,
      (__attribute__((address_space(3))) uint32_t*)l, 16, 0, 0);
}

// C[m,n] = sum_k A[m,k]*W[n,k] + bias[n]   (A: MxK bf16, W: NxK bf16 row-major)
// 256x128 block tile, BK=32, 4 waves each 64x128. bz selects stream.
template <bool RELU>
__global__ __launch_bounds__(256, 2) void gemm_bt(const u16* __restrict__ A0,
                                                  const u16* __restrict__ W0,
                                                  const float* __restrict__ bias0,
                                                  u16* __restrict__ C0,
                                                  const u16* __restrict__ A1,
                                                  const u16* __restrict__ W1,
                                                  const float* __restrict__ bias1,
                                                  u16* __restrict__ C1,
                                                  int M, int N, int K, int ldc) {
  // ---- XCD-aware bijective swizzle (T1) ----
  const int gx = gridDim.x, gy = gridDim.y, gz = gridDim.z;
  const int T = gx * gy * gz;
  const int l = blockIdx.x + gx * (blockIdx.y + gy * blockIdx.z);
  int bx, by, bz;
  if ((T & 7) == 0) {
    const int g = (l & 7) * (T >> 3) + (l >> 3);  // XCD (l&7) owns contiguous g-chunk
    bx = g % gx;
    const int rest = g / gx;
    by = rest % gy;
    bz = rest / gy;
  } else {
    bx = blockIdx.x; by = blockIdx.y; bz = blockIdx.z;
  }

  // 3 buffers x (A 256x32 = 16KB + B 128x32 = 8KB) = 72 KB
  __shared__ u16 sbuf[3 * 12288];
  const u16* A = bz ? A1 : A0;
  const u16* W = bz ? W1 : W0;
  const float* bias = bz ? bias1 : bias0;
  u16* Cout = bz ? C1 : C0;

  const int tid  = threadIdx.x;
  const int wave = tid >> 6;
  const int lane = tid & 63;
  const int m0 = by * 256;   // M-tile
  const int n0 = bx * 128;   // N-tile
  const int wm = wave * 64;
  const int fm   = lane & 15;
  const int quad = lane >> 4;

  const floatx4 zero = {0.f, 0.f, 0.f, 0.f};
  floatx4 acc[4][8];
#pragma unroll
  for (int i = 0; i < 4; ++i)
#pragma unroll
    for (int j = 0; j < 8; ++j) acc[i][j] = zero;

  // staging map (linear LDS, 16B/lane): each issue covers 16 rows x 32 cols.
  const int r4 = lane >> 2;          // 0..15
  const int c0 = (lane & 3) << 3;    // 0,8,16,24
  const u16* ApA = A + (size_t)(m0 + wave * 64 + r4) * K + c0;
  const u16* WpB = W + (size_t)(n0 + wave * 32 + r4) * K + c0;
  const size_t row16 = (size_t)16 * K;
  const int nt = K >> 5;             // BK=32 tiles (16 or 32 here)

  auto STAGE = [&](const u16* ap, const u16* wp, int b) {
    u16* base = sbuf + b * 12288;
#pragma unroll
    for (int q = 0; q < 4; ++q)
      gl_lds16(ap + (size_t)q * row16, base + (wave * 4 + q) * 512);
#pragma unroll
    for (int q = 0; q < 2; ++q)
      gl_lds16(wp + (size_t)q * row16, base + 8192 + (wave * 2 + q) * 512);
  };
  auto COMPUTE = [&](int b) {
    const u16* bA = sbuf + b * 12288;
    const u16* bB = bA + 8192;
    shortx8 af[4], bf[8];
#pragma unroll
    for (int i = 0; i < 4; ++i)
      af[i] = *(const shortx8*)(bA + (wm + i * 16 + fm) * 32 + quad * 8);
#pragma unroll
    for (int j = 0; j < 8; ++j)
      bf[j] = *(const shortx8*)(bB + (j * 16 + fm) * 32 + quad * 8);
    __builtin_amdgcn_s_setprio(1);
#pragma unroll
    for (int j = 0; j < 8; ++j)
#pragma unroll
      for (int i = 0; i < 4; ++i)
        acc[i][j] = __builtin_amdgcn_mfma_f32_16x16x32_bf16(af[i], bf[j], acc[i][j], 0, 0, 0);
    __builtin_amdgcn_s_setprio(0);
  };

  // prologue: tiles 0,1 -> buffers 0,1 (12 loads in flight)
  STAGE(ApA, WpB, 0);
  STAGE(ApA + 32, WpB + 32, 1);
  const u16* As = ApA + 64;
  const u16* Ws = WpB + 64;
  int sb = 2, cb = 0;

  for (int t = 0; t < nt - 1; ++t) {
    // retire tile t's 6 loads (leave tile t+1's 6 in flight), then sync.
    asm volatile("s_waitcnt vmcnt(6)\n\ts_barrier" ::: "memory");
    if (t < nt - 2) {
      STAGE(As, Ws, sb);
      As += 32;
      Ws += 32;
      sb = (sb == 2) ? 0 : sb + 1;
    }
    COMPUTE(cb);
    cb = (cb == 2) ? 0 : cb + 1;
  }
  asm volatile("s_waitcnt vmcnt(0)\n\ts_barrier" ::: "memory");
  COMPUTE(cb);

  // epilogue: C/D layout col=lane&15, row=quad*4+reg  (m89/m91 verified)
#pragma unroll
  for (int j = 0; j < 8; ++j) {
    const int col = n0 + j * 16 + fm;
    const float bj = bias ? bias[col] : 0.f;
#pragma unroll
    for (int i = 0; i < 4; ++i) {
      const int rb = m0 + wm + i * 16 + quad * 4;
#pragma unroll
      for (int r = 0; r < 4; ++r) {
        float v = acc[i][j][r] + bj;
        if (RELU) v = fmaxf(v, 0.f);
        Cout[(size_t)(rb + r) * ldc + col] = f2bf(v);
      }
    }
  }
}

// out = LN(resid_bf16 + add_bf16):  OUTF32=0 -> bf16 out (stride E, in-place on
// resid ok); OUTF32=1 -> f32 out (stride ld). blockIdx.y selects stream.
// One wave per row of 512; lane handles 8 consecutive elements.
template <int OUTF32>
__global__ __launch_bounds__(256) void ln_add_kernel(
    const u16* __restrict__ resid0, const u16* __restrict__ resid1,
    const u16* __restrict__ add0, const u16* __restrict__ add1,
    const float* __restrict__ g0, const float* __restrict__ b0,
    const float* __restrict__ g1, const float* __restrict__ b1,
    void* __restrict__ out0, void* __restrict__ out1, int ld) {
  const int ss = blockIdx.y;
  const u16* resid = ss ? resid1 : resid0;
  const u16* addv = ss ? add1 : add0;
  const float* g = ss ? g1 : g0;
  const float* b = ss ? b1 : b0;
  void* outp = ss ? out1 : out0;

  const int wave = threadIdx.x >> 6;
  const int lane = threadIdx.x & 63;
  const size_t row = (size_t)blockIdx.x * 4 + wave;
  const int col = lane * 8;
  float x[8];
  const u16x8 a = *(const u16x8*)(addv + row * E + col);
  const u16x8 rr = *(const u16x8*)(resid + row * E + col);
#pragma unroll
  for (int i = 0; i < 8; ++i) x[i] = bf2f(rr[i]) + bf2f(a[i]);
  float s = 0.f, sq = 0.f;
#pragma unroll
  for (int i = 0; i < 8; ++i) {
    s += x[i];
    sq += x[i] * x[i];
  }
#pragma unroll
  for (int off = 32; off > 0; off >>= 1) {
    s += __shfl_xor(s, off);
    sq += __shfl_xor(sq, off);
  }
  const float mean = s * (1.f / E);
  const float var = sq * (1.f / E) - mean * mean;
  const float rs = rsqrtf(var + LNEPS);
  const float4 g0v = *(const float4*)(g + col);
  const float4 g1v = *(const float4*)(g + col + 4);
  const float4 b0v = *(const float4*)(b + col);
  const float4 b1v = *(const float4*)(b + col + 4);
  float y[8];
  y[0] = (x[0] - mean) * rs * g0v.x + b0v.x;
  y[1] = (x[1] - mean) * rs * g0v.y + b0v.y;
  y[2] = (x[2] - mean) * rs * g0v.z + b0v.z;
  y[3] = (x[3] - mean) * rs * g0v.w + b0v.w;
  y[4] = (x[4] - mean) * rs * g1v.x + b1v.x;
  y[5] = (x[5] - mean) * rs * g1v.y + b1v.y;
  y[6] = (x[6] - mean) * rs * g1v.z + b1v.z;
  y[7] = (x[7] - mean) * rs * g1v.w + b1v.w;
  if (OUTF32 == 0) {
    u16x8 o;
#pragma unroll
    for (int i = 0; i < 8; ++i) o[i] = f2bf(y[i]);
    *(u16x8*)((u16*)outp + row * E + col) = o;
  } else {
    float* op = (float*)outp + row * ld + col;
    *(float4*)op = make_float4(y[0], y[1], y[2], y[3]);
    *(float4*)(op + 4) = make_float4(y[4], y[5], y[6], y[7]);
  }
}

// two input casts in one launch (blockIdx.y selects)
__global__ __launch_bounds__(256) void cast2_kernel(const float* __restrict__ in0,
                                                    const float* __restrict__ in1,
                                                    u16* __restrict__ o0,
                                                    u16* __restrict__ o1) {
  const float* in = blockIdx.y ? in1 : in0;
  u16* out = blockIdx.y ? o1 : o0;
  const size_t i = ((size_t)blockIdx.x * 256 + threadIdx.x) * 8;
  const float4 a = *(const float4*)(in + i);
  const float4 c = *(const float4*)(in + i + 4);
  u16x8 o;
  o[0] = f2bf(a.x); o[1] = f2bf(a.y); o[2] = f2bf(a.z); o[3] = f2bf(a.w);
  o[4] = f2bf(c.x); o[5] = f2bf(c.y); o[6] = f2bf(c.z); o[7] = f2bf(c.w);
  *(u16x8*)(out + i) = o;
}

// 6 weight casts in one launch: blocks [0,128) s0, [128,256) s1 (E*E each),
// [256,512) s2, [512,768) s3, [768,1024) s4, [1024,1280) s5 (2E*E each)
__global__ __launch_bounds__(256) void cast6_kernel(
    const float* __restrict__ s0, u16* __restrict__ d0,
    const float* __restrict__ s1, u16* __restrict__ d1,
    const float* __restrict__ s2, u16* __restrict__ d2,
    const float* __restrict__ s3, u16* __restrict__ d3,
    const float* __restrict__ s4, u16* __restrict__ d4,
    const float* __restrict__ s5, u16* __restrict__ d5) {
  int b = blockIdx.x;
  const float* in;
  u16* out;
  if (b < 256) {
    in = (b < 128) ? s0 : s1;
    out = (b < 128) ? d0 : d1;
    b &= 127;
  } else {
    const int t = (b - 256) >> 8;  // 0..3
    in = (t == 0) ? s2 : (t == 1) ? s3 : (t == 2) ? s4 : s5;
    out = (t == 0) ? d2 : (t == 1) ? d3 : (t == 2) ? d4 : d5;
    b = (b - 256) & 255;
  }
  const size_t i = ((size_t)b * 256 + threadIdx.x) * 8;
  const float4 a = *(const float4*)(in + i);
  const float4 c = *(const float4*)(in + i + 4);
  u16x8 o;
  o[0] = f2bf(a.x); o[1] = f2bf(a.y); o[2] = f2bf(a.z); o[3] = f2bf(a.w);
  o[4] = f2bf(c.x); o[5] = f2bf(c.y); o[6] = f2bf(c.z); o[7] = f2bf(c.w);
  *(u16x8*)(out + i) = o;
}

// out[k][j] = bf16(in[j][k]) for ExE; blockIdx.z selects stream
__global__ __launch_bounds__(256) void transpose_cast2_kernel(const float* __restrict__ in0,
                                                              u16* __restrict__ out0,
                                                              const float* __restrict__ in1,
                                                              u16* __restrict__ out1) {
  __shared__ float t[32][33];
  const float* in = blockIdx.z ? in1 : in0;
  u16* out = blockIdx.z ? out1 : out0;
  const int bx = blockIdx.x * 32;
  const int by = blockIdx.y * 32;
  const int x = threadIdx.x & 31;
  const int y0 = threadIdx.x >> 5;
#pragma unroll
  for (int y = y0; y < 32; y += 8) t[y][x] = in[(size_t)(by + y) * E + bx + x];
  __syncthreads();
#pragma unroll
  for (int y = y0; y < 32; y += 8) out[(size_t)(bx + y) * E + by + x] = f2bf(t[x][y]);
}

// bc[n] = dot(outw[n,:], bv) + outb[n]; n in [0,1024): n<512 stream A else B
__global__ __launch_bounds__(256) void combine_bias2_kernel(
    const float* __restrict__ outw1, const float* __restrict__ bv1,
    const float* __restrict__ outb1, float* __restrict__ bc1,
    const float* __restrict__ outw2, const float* __restrict__ bv2,
    const float* __restrict__ outb2, float* __restrict__ bc2) {
  int n = blockIdx.x * 256 + threadIdx.x;
  const float* outw = (n < E) ? outw1 : outw2;
  const float* bv = (n < E) ? bv1 : bv2;
  const float* outb = (n < E) ? outb1 : outb2;
  float* bc = (n < E) ? bc1 : bc2;
  n &= (E - 1);
  const float* wr = outw + (size_t)n * E;
  float s = 0.f;
  for (int j = 0; j < E; j += 4) {
    const float4 w4 = *(const float4*)(wr + j);
    const float4 v4 = *(const float4*)(bv + j);
    s += w4.x * v4.x + w4.y * v4.y + w4.z * v4.z + w4.w * v4.w;
  }
  bc[n] = s + outb[n];
}

extern "C" void kernel_launch(void* const* d_in, const int* in_sizes, int n_in,
                              void* d_out, int out_size, void* d_ws, size_t ws_size,
                              hipStream_t stream) {
  const float* dna      = (const float*)d_in[0];
  const float* mol      = (const float*)d_in[1];
  const float* a1_in_w  = (const float*)d_in[2];
  const float* a1_in_b  = (const float*)d_in[3];
  const float* a1_out_w = (const float*)d_in[4];
  const float* a1_out_b = (const float*)d_in[5];
  const float* a2_in_w  = (const float*)d_in[6];
  const float* a2_in_b  = (const float*)d_in[7];
  const float* a2_out_w = (const float*)d_in[8];
  const float* a2_out_b = (const float*)d_in[9];
  const float* ln1_g = (const float*)d_in[10];
  const float* ln1_b = (const float*)d_in[11];
  const float* ln2_g = (const float*)d_in[12];
  const float* ln2_b = (const float*)d_in[13];
  const float* ln3_g = (const float*)d_in[14];
  const float* ln3_b = (const float*)d_in[15];
  const float* ln4_g = (const float*)d_in[16];
  const float* ln4_b = (const float*)d_in[17];
  const float* f1_w1 = (const float*)d_in[18];
  const float* f1_b1 = (const float*)d_in[19];
  const float* f1_w2 = (const float*)d_in[20];
  const float* f1_b2 = (const float*)d_in[21];
  const float* f2_w1 = (const float*)d_in[22];
  const float* f2_b1 = (const float*)d_in[23];
  const float* f2_w2 = (const float*)d_in[24];
  const float* f2_b2 = (const float*)d_in[25];

  const int M = in_sizes[0] / E;  // 32768

  char* ws = (char*)d_ws;
  auto bump = [&](size_t sz) {
    char* p = ws;
    ws += (sz + 255) & ~(size_t)255;
    return p;
  };
  u16* wvT1   = (u16*)bump((size_t)E * E * 2);
  u16* wvT2   = (u16*)bump((size_t)E * E * 2);
  u16* outw1b = (u16*)bump((size_t)E * E * 2);
  u16* outw2b = (u16*)bump((size_t)E * E * 2);
  u16* Wc1    = (u16*)bump((size_t)E * E * 2);
  u16* Wc2    = (u16*)bump((size_t)E * E * 2);
  u16* fw11   = (u16*)bump((size_t)2 * E * E * 2);
  u16* fw12   = (u16*)bump((size_t)2 * E * E * 2);
  u16* fw21   = (u16*)bump((size_t)2 * E * E * 2);
  u16* fw22   = (u16*)bump((size_t)2 * E * E * 2);
  float* bc1  = (float*)bump(E * 4);
  float* bc2  = (float*)bump(E * 4);
  u16* X1  = (u16*)bump((size_t)M * E * 2);      // dna_bf, later y1
  u16* X2  = (u16*)bump((size_t)M * E * 2);      // mol_bf, later y2
  u16* Hb0 = (u16*)bump((size_t)M * 2 * E * 2);  // stream A FFN hidden
  u16* Hb1 = (u16*)bump((size_t)M * 2 * E * 2);  // stream B FFN hidden
  u16* Hc0 = (u16*)bump((size_t)M * E * 2);      // stream A attn out, later FFN2 out
  u16* Hc1 = (u16*)bump((size_t)M * E * 2);      // stream B attn out, later FFN2 out
  float* out_f = (float*)d_out;  // M x 2E, left=dna stream, right=mol stream

  // ---- weight prep (4 launches) ----
  transpose_cast2_kernel<<<dim3(16, 16, 2), 256, 0, stream>>>(
      a1_in_w + 2 * E * E, wvT1, a2_in_w + 2 * E * E, wvT2);
  cast6_kernel<<<1280, 256, 0, stream>>>(a1_out_w, outw1b, a2_out_w, outw2b,
                                         f1_w1, fw11, f1_w2, fw12, f2_w1, fw21, f2_w2, fw22);
  combine_bias2_kernel<<<4, 256, 0, stream>>>(a1_out_w, a1_in_b + 2 * E, a1_out_b, bc1,
                                              a2_out_w, a2_in_b + 2 * E, a2_out_b, bc2);
  // Wc[n,k] = sum_j out_w[n,j] * wv[j,k]  via gemm_bt(out_w, wv^T)  (M=N=K=512)
  gemm_bt<false><<<dim3(4, 2, 2), 256, 0, stream>>>(
      outw1b, wvT1, nullptr, Wc1, outw2b, wvT2, nullptr, Wc2, E, E, E, E);

  // ---- activations (6 launches) ----
  cast2_kernel<<<dim3((unsigned)((size_t)M * E / 2048), 2), 256, 0, stream>>>(dna, mol, X1, X2);
  // attn (softmax==1 -> pure projection with combined weights); A-stream uses X2!
  gemm_bt<false><<<dim3(4, M / 256, 2), 256, 0, stream>>>(
      X2, Wc1, bc1, Hc0, X1, Wc2, bc2, Hc1, M, E, E, E);
  // y = LN(x + attn), bf16 residual (X), in-place on X
  ln_add_kernel<0><<<dim3(M / 4, 2), 256, 0, stream>>>(
      X1, X2, Hc0, Hc1, ln1_g, ln1_b, ln2_g, ln2_b, X1, X2, E);
  // FFN hidden (relu)
  gemm_bt<true><<<dim3(8, M / 256, 2), 256, 0, stream>>>(
      X1, fw11, f1_b1, Hb0, X2, fw21, f2_b1, Hb1, M, 2 * E, E, 2 * E);
  // FFN out (bf16, overwrites dead attn buffers)
  gemm_bt<false><<<dim3(4, M / 256, 2), 256, 0, stream>>>(
      Hb0, fw12, f1_b2, Hc0, Hb1, fw22, f2_b2, Hc1, M, E, 2 * E, E);
  // final LN -> f32 d_out halves
  ln_add_kernel<1><<<dim3(M / 4, 2), 256, 0, stream>>>(
      X1, X2, Hc0, Hc1, ln3_g, ln3_b, ln4_g, ln4_b, out_f, out_f + E, 2 * E);
}